// Round 3
// baseline (586.236 us; speedup 1.0000x reference)
//
#include <hip/hip_runtime.h>
#include <hip/hip_bf16.h>

typedef __attribute__((ext_vector_type(8))) short short8;
typedef __attribute__((ext_vector_type(4))) float floatx4;

#define SCALE 0.17677669529663687f  /* 1/sqrt(32) */

__device__ __forceinline__ unsigned short f2bf(float f) {
  unsigned int x = __float_as_uint(f);
  x += 0x7fffu + ((x >> 16) & 1u);   // RNE
  return (unsigned short)(x >> 16);
}
__device__ __forceinline__ float bf2f(unsigned short u) {
  return __uint_as_float(((unsigned int)u) << 16);
}

// ================= fused prep: q = act@Wq (row-wise), then per-head fold =================
// Wave m owns row b = bt*4+m end-to-end; row B is the PMA seed. No cross-wave deps.
__global__ __launch_bounds__(256) void k_prep(
    const float* __restrict__ node, const int* __restrict__ tgt_idx,
    const float* __restrict__ seed,
    const float* __restrict__ Wq_c, const float* __restrict__ Wq_p,
    const float* __restrict__ Wk_c, const float* __restrict__ Wk_p,
    const int* __restrict__ port_batch,
    unsigned short* __restrict__ u_c_all, unsigned short* __restrict__ u_p_t,
    int* __restrict__ seg, int T, int B)
{
  __shared__ float act_l[4][256];
  __shared__ float q_l[4][256];
  const int tid = threadIdx.x;
  const int bt = blockIdx.x;
  const int BT = B >> 2;

  // segment starts via binary search (seg[0..B])
  {
    int key = -1;
    if (bt < BT) { if (tid < 4) key = bt * 4 + tid; }
    else if (tid == 0) key = B;
    if (key >= 0) {
      int lo = 0, hi = T;
      while (lo < hi) { int mid = (lo + hi) >> 1; if (port_batch[mid] < key) lo = mid + 1; else hi = mid; }
      seg[key] = lo;
    }
  }

  const int m = tid >> 6, lane = tid & 63;
  const int b = bt * 4 + m;
  if (b > B) return;

  // stage activation row (tgt or seed)
  {
    const float* src = (b < B) ? (node + (size_t)tgt_idx[b] * 256) : seed;
    *(floatx4*)&act_l[m][lane * 4] = *(const floatx4*)(src + lane * 4);
  }
  const float* Wq = (b == B) ? Wq_p : Wq_c;
  const float* Wk = (b == B) ? Wk_p : Wk_c;

  // q[c] = sum_k act[k] * Wq[k][c]; lane owns cols lane*4..+3 (coalesced 1KB/iter)
  {
    floatx4 acc = (floatx4){0.f, 0.f, 0.f, 0.f};
    #pragma unroll 4
    for (int k = 0; k < 256; ++k) {
      float a = act_l[m][k];
      floatx4 w = *(const floatx4*)(Wq + (size_t)k * 256 + lane * 4);
      acc[0] += a * w[0]; acc[1] += a * w[1]; acc[2] += a * w[2]; acc[3] += a * w[3];
    }
    *(floatx4*)&q_l[m][lane * 4] = acc;
  }

  // fold: u[h][d] = sum_{j<32} Wk[d][h*32+j] * q[h*32+j]
  // 2048 outputs / 64 lanes = 32 reps; rep r: h = r>>2, d = (r&3)*64 + lane
  #pragma unroll 1
  for (int r = 0; r < 32; ++r) {
    const int h = r >> 2, d = (r & 3) * 64 + lane;
    const float* wr = Wk + (size_t)d * 256 + h * 32;
    const float* qr = &q_l[m][h * 32];
    floatx4 a4 = (floatx4){0.f, 0.f, 0.f, 0.f};
    #pragma unroll
    for (int j4 = 0; j4 < 8; ++j4) {
      floatx4 w = *(const floatx4*)(wr + j4 * 4);
      floatx4 qq = *(const floatx4*)(qr + j4 * 4);
      a4[0] += w[0] * qq[0]; a4[1] += w[1] * qq[1];
      a4[2] += w[2] * qq[2]; a4[3] += w[3] * qq[3];
    }
    float acc = (a4[0] + a4[1]) + (a4[2] + a4[3]);
    unsigned short v = f2bf(acc);
    if (b < B) u_c_all[(size_t)b * 2048 + h * 256 + d] = v;
    else       u_p_t[h * 256 + d] = v;
  }
}

// ---------------- attention: WG (s, b) handles tiles s, s+S, ... of segment b ----------------
// Dense gather: each vmem instruction loads ONE full 1KB row (64 lanes x 16B contiguous),
// converts to bf16 via v_cvt_pk_bf16_f32, stages into LDS.
// LDS layout XOR-swizzled: in-row byte offset ^= ((row>>3)&3)<<5 (kills 8-way phase-2 conflict).
__global__ __launch_bounds__(256, 3) void attn_kernel(
    const float* __restrict__ node,
    const int* __restrict__ port_index,
    const float* __restrict__ port_weight,
    const unsigned short* __restrict__ u_p_t,
    const unsigned short* __restrict__ u_c_all,
    const int* __restrict__ seg,
    float* __restrict__ slabs, int T, int S)
{
  __shared__ __align__(16) unsigned short tok_lds[64 * 264];
  __shared__ __align__(16) unsigned short E_t[16 * 72];
  __shared__ float l_lds[16];

  const int tid  = threadIdx.x;
  const int s    = blockIdx.x;
  const int b    = blockIdx.y;
  const int lane = tid & 63;
  const int w    = tid >> 6;
  const int q    = lane >> 4;
  const int n    = lane & 15;

  if (tid < 16) l_lds[tid] = 0.f;

  short8 ufrag[8];
  const unsigned short* ubase = (n < 8) ? (u_p_t + n * 256)
                                        : (u_c_all + (size_t)b * 2048 + (n - 8) * 256);
  #pragma unroll
  for (int s8 = 0; s8 < 8; ++s8)
    ufrag[s8] = *(const short8*)(ubase + q * 8 + s8 * 32);

  const int start  = seg[b];
  const int end    = seg[b + 1];
  const int ntiles = (end - start + 63) >> 6;

  floatx4 sacc[4];
  #pragma unroll
  for (int nt = 0; nt < 4; ++nt) sacc[nt] = (floatx4){0.f, 0.f, 0.f, 0.f};

  __syncthreads();   // l_lds init visible

  for (int it = s; it < ntiles; it += S) {
    const int tbase = start + it * 64;
    // dense gather: wave w stages its 16 token rows (1KB each, fully contiguous)
    {
      int t0 = tbase + w * 16 + n;
      int idxv = port_index[t0 < T ? t0 : T - 1];
      #pragma unroll
      for (int i = 0; i < 16; ++i) {
        int rb = __shfl(idxv, i, 64);
        floatx4 v = *(const floatx4*)(node + (size_t)rb * 256 + lane * 4);
        uint2 pk;
        asm("v_cvt_pk_bf16_f32 %0, %1, %2" : "=v"(pk.x) : "v"(v[0]), "v"(v[1]));
        asm("v_cvt_pk_bf16_f32 %0, %1, %2" : "=v"(pk.y) : "v"(v[2]), "v"(v[3]));
        const int row = w * 16 + i;
        const int swz = ((row >> 3) & 3) << 5;
        *(uint2*)((char*)(tok_lds + row * 264) + ((lane * 8) ^ swz)) = pk;
      }
    }
    float pw[4];
    #pragma unroll
    for (int r = 0; r < 4; ++r) { int tr = tbase + w * 16 + q * 4 + r; pw[r] = port_weight[tr < T ? tr : T - 1]; }

    // phase 1: logits = tok_tile[16x256] @ U[256x16]; A-frags from LDS (own wave's rows)
    floatx4 lacc = (floatx4){0.f, 0.f, 0.f, 0.f};
    {
      const int rowA = w * 16 + n;
      const char* abase = (const char*)(tok_lds + rowA * 264);
      const int swzA = ((rowA >> 3) & 3) << 5;
      #pragma unroll
      for (int k = 0; k < 8; ++k) {
        short8 af = *(const short8*)(abase + ((q * 16 + k * 64) ^ swzA));
        lacc = __builtin_amdgcn_mfma_f32_16x16x32_bf16(af, ufrag[k], lacc, 0, 0, 0);
      }
    }
    float lsum = 0.f;
    #pragma unroll
    for (int r = 0; r < 4; ++r) {
      const int tr = tbase + w * 16 + q * 4 + r;
      float e = 0.f;
      if (tr < end) {
        // exp(l*scale + log(pw+eps)) == exp(l*scale) * (pw+eps) -- exact, no logf
        e = __expf(lacc[r] * SCALE) * (pw[r] + 1e-8f);
      }
      unsigned short eb = f2bf(e);
      E_t[n * 72 + w * 16 + q * 4 + r] = eb;       // E^T: [col][token]
      lsum += bf2f(eb);                            // denom consistent with bf16 e
    }
    lsum += __shfl_xor(lsum, 16, 64);
    lsum += __shfl_xor(lsum, 32, 64);
    if (lane < 16) atomicAdd(&l_lds[lane], lsum);
    __syncthreads();
    // phase 2: sums[16 cols][256 d] += E^T[16x64] @ tok[64x256]; wave w owns d slice
    short8 ea0 = *(const short8*)(E_t + n * 72 + q * 8);
    short8 ea1 = *(const short8*)(E_t + n * 72 + 32 + q * 8);
    const char* tbytes = (const char*)tok_lds;
    const int sq = q << 5;
    #pragma unroll
    for (int nt = 0; nt < 4; ++nt) {
      const int dx = ((w * 64 + nt * 16 + n) * 2) ^ sq;   // swizzled in-row byte offset
      short8 b0, b1;
      #pragma unroll
      for (int j = 0; j < 8; ++j) b0[j] = *(const short*)(tbytes + (q * 8 + j) * 528 + dx);
      #pragma unroll
      for (int j = 0; j < 8; ++j) b1[j] = *(const short*)(tbytes + (32 + q * 8 + j) * 528 + dx);
      sacc[nt] = __builtin_amdgcn_mfma_f32_16x16x32_bf16(ea0, b0, sacc[nt], 0, 0, 0);
      sacc[nt] = __builtin_amdgcn_mfma_f32_16x16x32_bf16(ea1, b1, sacc[nt], 0, 0, 0);
    }
    __syncthreads();
  }

  // epilogue: stage sacc through LDS (tok_lds free), coalesced float4 slab write
  float* stage = (float*)tok_lds;
  #pragma unroll
  for (int nt = 0; nt < 4; ++nt)
    #pragma unroll
    for (int r = 0; r < 4; ++r)
      stage[(q * 4 + r) * 256 + w * 64 + nt * 16 + n] = sacc[nt][r];
  __syncthreads();
  float* sl = slabs + ((size_t)b * S + s) * 4224;
  #pragma unroll
  for (int i = 0; i < 4; ++i) {
    const int row = i * 4 + w;
    const int c0 = (tid & 63) * 4;
    *(floatx4*)(sl + row * 256 + c0) = *(const floatx4*)(stage + row * 256 + c0);
  }
  if (tid < 16) sl[4096 + tid] = l_lds[tid];
}

// ================= fused tail: slab-reduce -> Wv -> Wo -> LN -> W1 -> W2 -> headW1 -> out ===
// Everything after the slabs is row-wise: wave m owns row b = blk*4+m end-to-end.
// No __syncthreads, no grid sync; per-wave private LDS slices (92 KB/block, 64 blocks).
__global__ __launch_bounds__(256) void k_tail(
    const float* __restrict__ slabs, int S,
    const float* __restrict__ Wv_p, const float* __restrict__ Wv_c,
    const float* __restrict__ Wo_p, const float* __restrict__ Wo_c,
    const float* __restrict__ node, const int* __restrict__ tgt_idx,
    const float* __restrict__ ln_g, const float* __restrict__ ln_b,
    const float* __restrict__ fuse_W1, const float* __restrict__ fuse_b1,
    const float* __restrict__ fuse_W2, const float* __restrict__ fuse_b2,
    const float* __restrict__ head_W1, const float* __restrict__ head_b1,
    const float* __restrict__ head_W2, const float* __restrict__ head_b2,
    float* __restrict__ out)
{
  __shared__ float pooled_l[4][16][256];  // 64 KB
  __shared__ float X_l[4][512];           // 8 KB
  __shared__ float zv[4][768];            // 12 KB
  __shared__ float hbuf[4][256];          // 4 KB
  __shared__ float hbuf2[4][256];         // 4 KB
  __shared__ float linv[4][16];

  const int tid = threadIdx.x;
  const int m = tid >> 6, lane = tid & 63;
  const int b = blockIdx.x * 4 + m;
  const float* sl0 = slabs + (size_t)b * S * 4224;

  // per-(z,head) normalizers
  if (lane < 16) {
    float l = 0.f;
    for (int s = 0; s < S; ++s) l += sl0[s * 4224 + 4096 + lane];
    linv[m][lane] = 1.0f / (l + 1e-9f);
  }
  // pooled[r][:] = (sum_s slab[s][r][:]) / l[r]
  #pragma unroll 1
  for (int r = 0; r < 16; ++r) {
    floatx4 p = (floatx4){0.f, 0.f, 0.f, 0.f};
    for (int s = 0; s < S; ++s) {
      floatx4 v = *(const floatx4*)(sl0 + s * 4224 + r * 256 + lane * 4);
      p[0] += v[0]; p[1] += v[1]; p[2] += v[2]; p[3] += v[3];
    }
    const float iv = linv[m][r];
    p[0] *= iv; p[1] *= iv; p[2] *= iv; p[3] *= iv;
    *(floatx4*)&pooled_l[m][r][lane * 4] = p;
  }

  // Wv: X[z*256 + h*32 + j] = dot(pooled[z*8+h][:], Wv_z[:, h*32+j])
  {
    const int j = lane & 31, kh = lane >> 5;
    #pragma unroll 1
    for (int z = 0; z < 2; ++z) {
      const float* Wv = z ? Wv_c : Wv_p;
      #pragma unroll 1
      for (int h = 0; h < 8; ++h) {
        const float* pr = &pooled_l[m][z * 8 + h][kh * 128];
        const float* wp = Wv + (size_t)(kh * 128) * 256 + h * 32 + j;
        float a0 = 0.f, a1 = 0.f, a2 = 0.f, a3 = 0.f;
        #pragma unroll 4
        for (int kk = 0; kk < 128; kk += 4) {
          a0 += pr[kk + 0] * wp[(size_t)(kk + 0) * 256];
          a1 += pr[kk + 1] * wp[(size_t)(kk + 1) * 256];
          a2 += pr[kk + 2] * wp[(size_t)(kk + 2) * 256];
          a3 += pr[kk + 3] * wp[(size_t)(kk + 3) * 256];
        }
        float acc = (a0 + a1) + (a2 + a3);
        acc += __shfl_xor(acc, 32, 64);
        if (kh == 0) X_l[m][z * 256 + h * 32 + j] = acc;
      }
    }
  }

  floatx4 tg4 = *(const floatx4*)(node + (size_t)tgt_idx[b] * 256 + lane * 4);

  // Wo: contexts = X[0:256]@Wo_p ; fused = tgt + X[256:512]@Wo_c
  #pragma unroll 1
  for (int z = 0; z < 2; ++z) {
    const float* Wo = z ? Wo_c : Wo_p;
    floatx4 acc = (floatx4){0.f, 0.f, 0.f, 0.f};
    #pragma unroll 4
    for (int k = 0; k < 256; ++k) {
      float a = X_l[m][z * 256 + k];
      floatx4 w = *(const floatx4*)(Wo + (size_t)k * 256 + lane * 4);
      acc[0] += a * w[0]; acc[1] += a * w[1]; acc[2] += a * w[2]; acc[3] += a * w[3];
    }
    if (z == 0) {
      *(floatx4*)&zv[m][256 + lane * 4] = acc;
    } else {
      acc[0] += tg4[0]; acc[1] += tg4[1]; acc[2] += tg4[2]; acc[3] += tg4[3];
      *(floatx4*)&zv[m][512 + lane * 4] = acc;
    }
  }
  *(floatx4*)&zv[m][lane * 4] = tg4;

  // LayerNorm over 768 (per-wave)
  {
    float sv = 0.f;
    for (int k = lane; k < 768; k += 64) sv += zv[m][k];
    #pragma unroll
    for (int o = 32; o >= 1; o >>= 1) sv += __shfl_xor(sv, o, 64);
    const float mu = sv * (1.0f / 768.0f);
    float vv = 0.f;
    for (int k = lane; k < 768; k += 64) { float d = zv[m][k] - mu; vv += d * d; }
    #pragma unroll
    for (int o = 32; o >= 1; o >>= 1) vv += __shfl_xor(vv, o, 64);
    const float rstd = 1.0f / sqrtf(vv * (1.0f / 768.0f) + 1e-5f);
    for (int k = lane; k < 768; k += 64)
      zv[m][k] = (zv[m][k] - mu) * rstd * ln_g[k] + ln_b[k];
  }

  // fuse_W1 (K=768) + relu -> hbuf
  {
    floatx4 acc = (floatx4){0.f, 0.f, 0.f, 0.f};
    #pragma unroll 4
    for (int k = 0; k < 768; ++k) {
      float a = zv[m][k];
      floatx4 w = *(const floatx4*)(fuse_W1 + (size_t)k * 256 + lane * 4);
      acc[0] += a * w[0]; acc[1] += a * w[1]; acc[2] += a * w[2]; acc[3] += a * w[3];
    }
    floatx4 bb = *(const floatx4*)(fuse_b1 + lane * 4);
    acc[0] = fmaxf(acc[0] + bb[0], 0.f); acc[1] = fmaxf(acc[1] + bb[1], 0.f);
    acc[2] = fmaxf(acc[2] + bb[2], 0.f); acc[3] = fmaxf(acc[3] + bb[3], 0.f);
    *(floatx4*)&hbuf[m][lane * 4] = acc;
  }
  // fuse_W2 (K=256) -> hbuf2
  {
    floatx4 acc = (floatx4){0.f, 0.f, 0.f, 0.f};
    #pragma unroll 4
    for (int k = 0; k < 256; ++k) {
      float a = hbuf[m][k];
      floatx4 w = *(const floatx4*)(fuse_W2 + (size_t)k * 256 + lane * 4);
      acc[0] += a * w[0]; acc[1] += a * w[1]; acc[2] += a * w[2]; acc[3] += a * w[3];
    }
    floatx4 bb = *(const floatx4*)(fuse_b2 + lane * 4);
    acc[0] += bb[0]; acc[1] += bb[1]; acc[2] += bb[2]; acc[3] += bb[3];
    *(floatx4*)&hbuf2[m][lane * 4] = acc;
  }
  // head_W1 (K=256) + relu -> hbuf (h1 dead, reuse)
  {
    floatx4 acc = (floatx4){0.f, 0.f, 0.f, 0.f};
    #pragma unroll 4
    for (int k = 0; k < 256; ++k) {
      float a = hbuf2[m][k];
      floatx4 w = *(const floatx4*)(head_W1 + (size_t)k * 256 + lane * 4);
      acc[0] += a * w[0]; acc[1] += a * w[1]; acc[2] += a * w[2]; acc[3] += a * w[3];
    }
    floatx4 bb = *(const floatx4*)(head_b1 + lane * 4);
    acc[0] = fmaxf(acc[0] + bb[0], 0.f); acc[1] = fmaxf(acc[1] + bb[1], 0.f);
    acc[2] = fmaxf(acc[2] + bb[2], 0.f); acc[3] = fmaxf(acc[3] + bb[3], 0.f);
    *(floatx4*)&hbuf[m][lane * 4] = acc;
  }
  // head_W2 (256 -> 3)
  {
    float a0 = 0.f, a1 = 0.f, a2 = 0.f;
    for (int k = lane; k < 256; k += 64) {
      float h = hbuf[m][k];
      a0 += h * head_W2[k * 3 + 0];
      a1 += h * head_W2[k * 3 + 1];
      a2 += h * head_W2[k * 3 + 2];
    }
    #pragma unroll
    for (int o = 32; o >= 1; o >>= 1) {
      a0 += __shfl_xor(a0, o, 64);
      a1 += __shfl_xor(a1, o, 64);
      a2 += __shfl_xor(a2, o, 64);
    }
    if (lane == 0) {
      out[b * 3 + 0] = a0 + head_b2[0];
      out[b * 3 + 1] = a1 + head_b2[1];
      out[b * 3 + 2] = a2 + head_b2[2];
    }
  }
}

extern "C" void kernel_launch(void* const* d_in, const int* in_sizes, int n_in,
                              void* d_out, int out_size, void* d_ws, size_t ws_size,
                              hipStream_t stream) {
  const float* node        = (const float*)d_in[0];
  const int*   tgt_idx     = (const int*)d_in[1];
  const int*   port_index  = (const int*)d_in[2];
  const int*   port_batch  = (const int*)d_in[3];
  const float* port_weight = (const float*)d_in[4];
  const float* seed        = (const float*)d_in[5];
  const float* Wq_p = (const float*)d_in[6];
  const float* Wk_p = (const float*)d_in[7];
  const float* Wv_p = (const float*)d_in[8];
  const float* Wo_p = (const float*)d_in[9];
  const float* Wq_c = (const float*)d_in[10];
  const float* Wk_c = (const float*)d_in[11];
  const float* Wv_c = (const float*)d_in[12];
  const float* Wo_c = (const float*)d_in[13];
  const float* ln_g = (const float*)d_in[14];
  const float* ln_b = (const float*)d_in[15];
  const float* fuse_W1 = (const float*)d_in[16];
  const float* fuse_b1 = (const float*)d_in[17];
  const float* fuse_W2 = (const float*)d_in[18];
  const float* fuse_b2 = (const float*)d_in[19];
  const float* head_W1 = (const float*)d_in[20];
  const float* head_b1 = (const float*)d_in[21];
  const float* head_W2 = (const float*)d_in[22];
  const float* head_b2 = (const float*)d_in[23];

  const int B = in_sizes[1];
  const int T = in_sizes[2];

  char* ws = (char*)d_ws;
  unsigned short* u_p_t   = (unsigned short*)ws;
  int*            seg     = (int*)(ws + 4096);
  unsigned short* u_c_all = (unsigned short*)(ws + 8192);
  size_t slab_off = 8192 + (size_t)B * 4096;
  float* slabs = (float*)(ws + slab_off);

  size_t per_slice = (size_t)B * 4224 * 4;
  int S = 1;
  if (ws_size > slab_off + per_slice) {
    size_t fit = (ws_size - slab_off - ((size_t)(B + 1) * 1024 + 4096)) / per_slice;
    S = (int)(fit < 1 ? 1 : (fit > 4 ? 4 : fit));   // S=4: 4 WGs/CU, ~2 tiles/WG
  }

  const int BT = B / 4;   // 64 b-tiles

  k_prep<<<dim3(BT + 1), 256, 0, stream>>>(node, tgt_idx, seed,
      Wq_c, Wq_p, Wk_c, Wk_p, port_batch, u_c_all, u_p_t, seg, T, B);
  attn_kernel<<<dim3(S, B), 256, 0, stream>>>(node, port_index, port_weight,
      u_p_t, u_c_all, seg, slabs, T, S);
  k_tail<<<dim3(BT), 256, 0, stream>>>(slabs, S, Wv_p, Wv_c, Wo_p, Wo_c,
      node, tgt_idx, ln_g, ln_b, fuse_W1, fuse_b1, fuse_W2, fuse_b2,
      head_W1, head_b1, head_W2, head_b2, (float*)d_out);
}

// Round 4
// 303.133 us; speedup vs baseline: 1.9339x; 1.9339x over previous
//
#include <hip/hip_runtime.h>
#include <hip/hip_bf16.h>

typedef __attribute__((ext_vector_type(8))) short short8;
typedef __attribute__((ext_vector_type(4))) float floatx4;

#define SCALE 0.17677669529663687f  /* 1/sqrt(32) */

__device__ __forceinline__ unsigned short f2bf(float f) {
  unsigned int x = __float_as_uint(f);
  x += 0x7fffu + ((x >> 16) & 1u);   // RNE
  return (unsigned short)(x >> 16);
}
__device__ __forceinline__ float bf2f(unsigned short u) {
  return __uint_as_float(((unsigned int)u) << 16);
}

// ---------------- setup A: q_all[b,:] = tgt_b @ Wq_c  (row B = seed @ Wq_p) ----------------
__global__ __launch_bounds__(256) void k_qc_gemm(
    const float* __restrict__ node, const int* __restrict__ tgt_idx,
    const float* __restrict__ seed,
    const float* __restrict__ Wq_c, const float* __restrict__ Wq_p,
    float* __restrict__ q_all, int B)
{
  __shared__ float act_l[4 * 256];
  const int tid = threadIdx.x;
  const int bt = blockIdx.x, nt = blockIdx.y;
  const int BT = B >> 2;
  for (int i = tid; i < 4 * 256; i += 256) {
    int m = i >> 8, k = i & 255;
    int b = bt * 4 + m;
    float v = 0.f;
    if (b < B)       v = node[(size_t)tgt_idx[b] * 256 + k];
    else if (b == B) v = seed[k];
    act_l[i] = v;
  }
  __syncthreads();
  const float* W = (bt == BT) ? Wq_p : Wq_c;
  const int m = tid >> 6, lane = tid & 63, ks = lane >> 4, n = lane & 15;
  const int n0 = nt * 16;
  float acc = 0.f;
  const float* Wp = W + (size_t)(ks * 64) * 256 + n0 + n;
  const float* ap = &act_l[m * 256 + ks * 64];
  #pragma unroll 8
  for (int k = 0; k < 64; ++k) acc += ap[k] * Wp[(size_t)k * 256];
  acc += __shfl_xor(acc, 16, 64);
  acc += __shfl_xor(acc, 32, 64);
  const int b = bt * 4 + m;
  if (ks == 0 && b <= B) q_all[(size_t)b * 256 + n0 + n] = acc;
}

// ---------------- setup B: per-head fold u[b][h][d] = sum_j Wk[d, h*32+j] q[b, h*32+j] ----------------
__global__ __launch_bounds__(256) void k_fold(
    const float* __restrict__ Wk_c, const float* __restrict__ Wk_p,
    const float* __restrict__ q_all, const int* __restrict__ port_batch,
    unsigned short* __restrict__ u_c_all, unsigned short* __restrict__ u_p_t,
    int* __restrict__ seg, int T, int B)
{
  const int tid = threadIdx.x;
  const int bt = blockIdx.x, dt = blockIdx.y;
  const int BT = B >> 2;
  if (dt == 0) {
    int key = -1;
    if (bt < BT) { if (tid < 4) key = bt * 4 + tid; }
    else if (tid == 0) key = B;
    if (key >= 0) {
      int lo = 0, hi = T;
      while (lo < hi) { int mid = (lo + hi) >> 1; if (port_batch[mid] < key) lo = mid + 1; else hi = mid; }
      seg[key] = lo;
    }
  }
  const int m = tid >> 6, lane = tid & 63;
  const int b = bt * 4 + m;
  if (b > B) return;
  const float* Wk = (b == B) ? Wk_p : Wk_c;
  const float* q = q_all + (size_t)b * 256;
  #pragma unroll
  for (int t2 = 0; t2 < 2; ++t2) {
    const int idx = t2 * 64 + lane;
    const int h = idx >> 4;
    const int d = dt * 16 + (idx & 15);
    float acc = 0.f;
    const float* wr = Wk + (size_t)d * 256 + h * 32;
    const float* qr = q + h * 32;
    #pragma unroll 8
    for (int j = 0; j < 32; ++j) acc += wr[j] * qr[j];
    unsigned short v = f2bf(acc);
    if (b < B) u_c_all[(size_t)b * 2048 + h * 256 + d] = v;
    else       u_p_t[h * 256 + d] = v;
  }
}

// ---------------- attention: WG (s, b) handles tiles s, s+S, ... of segment b ----------------
// Dense gather: each vmem instruction loads ONE full 1KB row (64 lanes x 16B contiguous),
// converts to bf16 via v_cvt_pk_bf16_f32, stages into LDS.
// LDS layout XOR-swizzled: in-row byte offset ^= ((row>>3)&3)<<5 (kills 8-way phase-2 conflict).
__global__ __launch_bounds__(256, 3) void attn_kernel(
    const float* __restrict__ node,
    const int* __restrict__ port_index,
    const float* __restrict__ port_weight,
    const unsigned short* __restrict__ u_p_t,
    const unsigned short* __restrict__ u_c_all,
    const int* __restrict__ seg,
    float* __restrict__ slabs, int T, int S)
{
  __shared__ __align__(16) unsigned short tok_lds[64 * 264];
  __shared__ __align__(16) unsigned short E_t[16 * 72];
  __shared__ float l_lds[16];

  const int tid  = threadIdx.x;
  const int s    = blockIdx.x;
  const int b    = blockIdx.y;
  const int lane = tid & 63;
  const int w    = tid >> 6;
  const int q    = lane >> 4;
  const int n    = lane & 15;

  if (tid < 16) l_lds[tid] = 0.f;

  short8 ufrag[8];
  const unsigned short* ubase = (n < 8) ? (u_p_t + n * 256)
                                        : (u_c_all + (size_t)b * 2048 + (n - 8) * 256);
  #pragma unroll
  for (int s8 = 0; s8 < 8; ++s8)
    ufrag[s8] = *(const short8*)(ubase + q * 8 + s8 * 32);

  const int start  = seg[b];
  const int end    = seg[b + 1];
  const int ntiles = (end - start + 63) >> 6;

  floatx4 sacc[4];
  #pragma unroll
  for (int nt = 0; nt < 4; ++nt) sacc[nt] = (floatx4){0.f, 0.f, 0.f, 0.f};

  __syncthreads();   // l_lds init visible

  for (int it = s; it < ntiles; it += S) {
    const int tbase = start + it * 64;
    // dense gather: wave w stages its 16 token rows (1KB each, fully contiguous)
    {
      int t0 = tbase + w * 16 + n;
      int idxv = port_index[t0 < T ? t0 : T - 1];
      #pragma unroll
      for (int i = 0; i < 16; ++i) {
        int rb = __shfl(idxv, i, 64);
        floatx4 v = *(const floatx4*)(node + (size_t)rb * 256 + lane * 4);
        uint2 pk;
        asm("v_cvt_pk_bf16_f32 %0, %1, %2" : "=v"(pk.x) : "v"(v[0]), "v"(v[1]));
        asm("v_cvt_pk_bf16_f32 %0, %1, %2" : "=v"(pk.y) : "v"(v[2]), "v"(v[3]));
        const int row = w * 16 + i;
        const int swz = ((row >> 3) & 3) << 5;
        *(uint2*)((char*)(tok_lds + row * 264) + ((lane * 8) ^ swz)) = pk;
      }
    }
    float pw[4];
    #pragma unroll
    for (int r = 0; r < 4; ++r) { int tr = tbase + w * 16 + q * 4 + r; pw[r] = port_weight[tr < T ? tr : T - 1]; }

    // phase 1: logits = tok_tile[16x256] @ U[256x16]; A-frags from LDS (own wave's rows)
    floatx4 lacc = (floatx4){0.f, 0.f, 0.f, 0.f};
    {
      const int rowA = w * 16 + n;
      const char* abase = (const char*)(tok_lds + rowA * 264);
      const int swzA = ((rowA >> 3) & 3) << 5;
      #pragma unroll
      for (int k = 0; k < 8; ++k) {
        short8 af = *(const short8*)(abase + ((q * 16 + k * 64) ^ swzA));
        lacc = __builtin_amdgcn_mfma_f32_16x16x32_bf16(af, ufrag[k], lacc, 0, 0, 0);
      }
    }
    float lsum = 0.f;
    #pragma unroll
    for (int r = 0; r < 4; ++r) {
      const int tr = tbase + w * 16 + q * 4 + r;
      float e = 0.f;
      if (tr < end) {
        // exp(l*scale + log(pw+eps)) == exp(l*scale) * (pw+eps) -- exact, no logf
        e = __expf(lacc[r] * SCALE) * (pw[r] + 1e-8f);
      }
      unsigned short eb = f2bf(e);
      E_t[n * 72 + w * 16 + q * 4 + r] = eb;       // E^T: [col][token]
      lsum += bf2f(eb);                            // denom consistent with bf16 e
    }
    lsum += __shfl_xor(lsum, 16, 64);
    lsum += __shfl_xor(lsum, 32, 64);
    if (lane < 16) atomicAdd(&l_lds[lane], lsum);
    __syncthreads();
    // phase 2: sums[16 cols][256 d] += E^T[16x64] @ tok[64x256]; wave w owns d slice
    short8 ea0 = *(const short8*)(E_t + n * 72 + q * 8);
    short8 ea1 = *(const short8*)(E_t + n * 72 + 32 + q * 8);
    const char* tbytes = (const char*)tok_lds;
    const int sq = q << 5;
    #pragma unroll
    for (int nt = 0; nt < 4; ++nt) {
      const int dx = ((w * 64 + nt * 16 + n) * 2) ^ sq;   // swizzled in-row byte offset
      short8 b0, b1;
      #pragma unroll
      for (int j = 0; j < 8; ++j) b0[j] = *(const short*)(tbytes + (q * 8 + j) * 528 + dx);
      #pragma unroll
      for (int j = 0; j < 8; ++j) b1[j] = *(const short*)(tbytes + (32 + q * 8 + j) * 528 + dx);
      sacc[nt] = __builtin_amdgcn_mfma_f32_16x16x32_bf16(ea0, b0, sacc[nt], 0, 0, 0);
      sacc[nt] = __builtin_amdgcn_mfma_f32_16x16x32_bf16(ea1, b1, sacc[nt], 0, 0, 0);
    }
    __syncthreads();
  }

  // epilogue: stage sacc through LDS (tok_lds free), coalesced float4 slab write
  float* stage = (float*)tok_lds;
  #pragma unroll
  for (int nt = 0; nt < 4; ++nt)
    #pragma unroll
    for (int r = 0; r < 4; ++r)
      stage[(q * 4 + r) * 256 + w * 64 + nt * 16 + n] = sacc[nt][r];
  __syncthreads();
  float* sl = slabs + ((size_t)b * S + s) * 4224;
  #pragma unroll
  for (int i = 0; i < 4; ++i) {
    const int row = i * 4 + w;
    const int c0 = (tid & 63) * 4;
    *(floatx4*)(sl + row * 256 + c0) = *(const floatx4*)(stage + row * 256 + c0);
  }
  if (tid < 16) sl[4096 + tid] = l_lds[tid];
}

// ============ staged finalize: batched 4x16 output tiles, K-split waves ============
__global__ __launch_bounds__(256) void k_slab_gemm(
    const float* __restrict__ slabs, int S,
    const float* __restrict__ Wv_p, const float* __restrict__ Wv_c,
    float* __restrict__ X)
{
  __shared__ float act_l[4 * 256];
  __shared__ float lsum[4];
  const int tid = threadIdx.x;
  const int bt = blockIdx.x, nt = blockIdx.y, z = blockIdx.z;
  const int head = nt >> 1;
  const int row = z * 8 + head;
  if (tid < 4) {
    const float* sl = slabs + (size_t)(bt * 4 + tid) * S * 4224;
    float l = 0.f;
    for (int s = 0; s < S; ++s) l += sl[s * 4224 + 4096 + row];
    lsum[tid] = 1.0f / (l + 1e-9f);
  }
  __syncthreads();
  for (int i = tid; i < 4 * 256; i += 256) {
    int m = i >> 8, k = i & 255;
    const float* sl = slabs + (size_t)(bt * 4 + m) * S * 4224;
    float sum = 0.f;
    for (int s = 0; s < S; ++s) sum += sl[s * 4224 + row * 256 + k];
    act_l[i] = sum * lsum[m];
  }
  __syncthreads();
  const int m = tid >> 6, lane = tid & 63, ks = lane >> 4, n = lane & 15;
  const int n0 = nt * 16;
  const float* W = z ? Wv_c : Wv_p;
  float acc = 0.f;
  const float* Wp = W + (size_t)(ks * 64) * 256 + n0 + n;
  const float* ap = &act_l[m * 256 + ks * 64];
  #pragma unroll 8
  for (int k = 0; k < 64; ++k) acc += ap[k] * Wp[(size_t)k * 256];
  acc += __shfl_xor(acc, 16, 64);
  acc += __shfl_xor(acc, 32, 64);
  if (ks == 0)
    X[(size_t)(bt * 4 + m) * 512 + z * 256 + n0 + n] = acc;
}

__global__ __launch_bounds__(256) void k_plain_gemm(
    const float* __restrict__ act, int act_ld,
    const float* __restrict__ W0, const float* __restrict__ W1,
    const float* __restrict__ bias0, const float* __restrict__ bias1,
    float* __restrict__ outp, int out_ld,
    int K, int relu)
{
  __shared__ float act_l[4 * 768];
  const int tid = threadIdx.x;
  const int bt = blockIdx.x, nt = blockIdx.y, z = blockIdx.z;
  const float* W = z ? W1 : W0;
  const float* bias = z ? bias1 : bias0;
  for (int i = tid; i < 4 * K; i += 256) {
    int m = i / K, k = i - m * K;
    act_l[m * K + k] = act[(size_t)(bt * 4 + m) * act_ld + z * K + k];
  }
  __syncthreads();
  const int m = tid >> 6, lane = tid & 63, ks = lane >> 4, n = lane & 15;
  const int n0 = nt * 16;
  const int Kq = K >> 2;
  float acc = 0.f;
  const float* Wp = W + (size_t)(ks * Kq) * 256 + n0 + n;
  const float* ap = &act_l[m * K + ks * Kq];
  #pragma unroll 8
  for (int k = 0; k < Kq; ++k) acc += ap[k] * Wp[(size_t)k * 256];
  acc += __shfl_xor(acc, 16, 64);
  acc += __shfl_xor(acc, 32, 64);
  if (ks == 0) {
    float v = acc + (bias ? bias[n0 + n] : 0.f);
    if (relu) v = fmaxf(v, 0.f);
    outp[(size_t)(bt * 4 + m) * out_ld + z * 256 + n0 + n] = v;
  }
}

__global__ __launch_bounds__(256) void k_ln_gemm(
    const float* __restrict__ node, const int* __restrict__ tgt_idx,
    const float* __restrict__ zbuf,
    const float* __restrict__ ln_g, const float* __restrict__ ln_b,
    const float* __restrict__ fuse_W1, const float* __restrict__ fuse_b1,
    float* __restrict__ h1)
{
  __shared__ float act_l[4 * 768];
  const int tid = threadIdx.x;
  const int bt = blockIdx.x, nt = blockIdx.y;
  for (int i = tid; i < 4 * 256; i += 256) {
    int m = i >> 8, k = i & 255;
    int b = bt * 4 + m;
    float tg = node[(size_t)tgt_idx[b] * 256 + k];
    float C  = zbuf[(size_t)b * 512 + k];
    float Fp = zbuf[(size_t)b * 512 + 256 + k];
    act_l[m * 768 + k]       = tg;
    act_l[m * 768 + 256 + k] = C;
    act_l[m * 768 + 512 + k] = tg + Fp;
  }
  __syncthreads();
  const int m = tid >> 6, lane = tid & 63;
  {
    float s = 0.f;
    for (int k = lane; k < 768; k += 64) s += act_l[m * 768 + k];
    #pragma unroll
    for (int o = 32; o >= 1; o >>= 1) s += __shfl_xor(s, o, 64);
    const float mu = s * (1.0f / 768.0f);
    float v = 0.f;
    for (int k = lane; k < 768; k += 64) { float d = act_l[m * 768 + k] - mu; v += d * d; }
    #pragma unroll
    for (int o = 32; o >= 1; o >>= 1) v += __shfl_xor(v, o, 64);
    const float rstd = 1.0f / sqrtf(v * (1.0f / 768.0f) + 1e-5f);
    for (int k = lane; k < 768; k += 64)
      act_l[m * 768 + k] = (act_l[m * 768 + k] - mu) * rstd * ln_g[k] + ln_b[k];
  }
  __syncthreads();
  const int ks = lane >> 4, n = lane & 15;
  const int n0 = nt * 16;
  float acc = 0.f;
  const float* Wp = fuse_W1 + (size_t)(ks * 192) * 256 + n0 + n;
  const float* ap = &act_l[m * 768 + ks * 192];
  #pragma unroll 8
  for (int k = 0; k < 192; ++k) acc += ap[k] * Wp[(size_t)k * 256];
  acc += __shfl_xor(acc, 16, 64);
  acc += __shfl_xor(acc, 32, 64);
  if (ks == 0)
    h1[(size_t)(bt * 4 + m) * 256 + n0 + n] = fmaxf(acc + fuse_b1[n0 + n], 0.f);
}

// ============ merged last 3 stages: z2 = h1@W2+b2; hh = relu(z2@hW1+b1); out = hh@hW2+b2 ====
// ONE block per row b (256 blocks -> every CU busy), K split 4-ways across waves,
// 64-iteration coalesced per-wave loops, LDS partial-reduce. 6 KB LDS.
// Reduction grouping matches the old ks-split kernels: (p0+p1)+(p2+p3).
__global__ __launch_bounds__(256) void k_tail3(
    const float* __restrict__ h1,
    const float* __restrict__ fuse_W2, const float* __restrict__ fuse_b2,
    const float* __restrict__ head_W1, const float* __restrict__ head_b1,
    const float* __restrict__ head_W2, const float* __restrict__ head_b2,
    float* __restrict__ out)
{
  __shared__ float a_l[256];
  __shared__ float part[4][256];
  __shared__ float red[12];
  const int tid = threadIdx.x;
  const int b = blockIdx.x;
  const int ks = tid >> 6, lane = tid & 63;

  a_l[tid] = h1[(size_t)b * 256 + tid];
  __syncthreads();

  // stage 1: z2 = a @ fuse_W2 + b2   (K=256 split as 4 x 64 across waves)
  {
    floatx4 acc = (floatx4){0.f, 0.f, 0.f, 0.f};
    const float* ap = &a_l[ks * 64];
    const float* wp = fuse_W2 + (size_t)(ks * 64) * 256 + lane * 4;
    #pragma unroll 4
    for (int k = 0; k < 64; ++k) {
      float a = ap[k];
      floatx4 w = *(const floatx4*)(wp + (size_t)k * 256);
      acc[0] += a * w[0]; acc[1] += a * w[1]; acc[2] += a * w[2]; acc[3] += a * w[3];
    }
    *(floatx4*)&part[ks][lane * 4] = acc;
  }
  __syncthreads();
  {
    float v = (part[0][tid] + part[1][tid]) + (part[2][tid] + part[3][tid]) + fuse_b2[tid];
    __syncthreads();           // everyone done reading part & a_l before overwrite
    a_l[tid] = v;
  }
  __syncthreads();

  // stage 2: hh = relu(z2 @ head_W1 + b1)
  {
    floatx4 acc = (floatx4){0.f, 0.f, 0.f, 0.f};
    const float* ap = &a_l[ks * 64];
    const float* wp = head_W1 + (size_t)(ks * 64) * 256 + lane * 4;
    #pragma unroll 4
    for (int k = 0; k < 64; ++k) {
      float a = ap[k];
      floatx4 w = *(const floatx4*)(wp + (size_t)k * 256);
      acc[0] += a * w[0]; acc[1] += a * w[1]; acc[2] += a * w[2]; acc[3] += a * w[3];
    }
    *(floatx4*)&part[ks][lane * 4] = acc;
  }
  __syncthreads();
  {
    float v = (part[0][tid] + part[1][tid]) + (part[2][tid] + part[3][tid]) + head_b1[tid];
    v = fmaxf(v, 0.f);
    __syncthreads();
    a_l[tid] = v;
  }
  __syncthreads();

  // stage 3: out = hh @ head_W2 + b2   (K split 4 ways, wave shfl-reduce, LDS combine)
  {
    float a0 = 0.f, a1 = 0.f, a2 = 0.f;
    for (int k = ks * 64 + lane; k < ks * 64 + 64; k += 64) {
      float h = a_l[k];
      a0 += h * head_W2[k * 3 + 0];
      a1 += h * head_W2[k * 3 + 1];
      a2 += h * head_W2[k * 3 + 2];
    }
    #pragma unroll
    for (int o = 32; o >= 1; o >>= 1) {
      a0 += __shfl_xor(a0, o, 64);
      a1 += __shfl_xor(a1, o, 64);
      a2 += __shfl_xor(a2, o, 64);
    }
    if (lane == 0) { red[ks * 3 + 0] = a0; red[ks * 3 + 1] = a1; red[ks * 3 + 2] = a2; }
  }
  __syncthreads();
  if (tid < 3) {
    out[b * 3 + tid] = (red[0 + tid] + red[3 + tid]) + (red[6 + tid] + red[9 + tid])
                       + head_b2[tid];
  }
}

extern "C" void kernel_launch(void* const* d_in, const int* in_sizes, int n_in,
                              void* d_out, int out_size, void* d_ws, size_t ws_size,
                              hipStream_t stream) {
  const float* node        = (const float*)d_in[0];
  const int*   tgt_idx     = (const int*)d_in[1];
  const int*   port_index  = (const int*)d_in[2];
  const int*   port_batch  = (const int*)d_in[3];
  const float* port_weight = (const float*)d_in[4];
  const float* seed        = (const float*)d_in[5];
  const float* Wq_p = (const float*)d_in[6];
  const float* Wk_p = (const float*)d_in[7];
  const float* Wv_p = (const float*)d_in[8];
  const float* Wo_p = (const float*)d_in[9];
  const float* Wq_c = (const float*)d_in[10];
  const float* Wk_c = (const float*)d_in[11];
  const float* Wv_c = (const float*)d_in[12];
  const float* Wo_c = (const float*)d_in[13];
  const float* ln_g = (const float*)d_in[14];
  const float* ln_b = (const float*)d_in[15];
  const float* fuse_W1 = (const float*)d_in[16];
  const float* fuse_b1 = (const float*)d_in[17];
  const float* fuse_W2 = (const float*)d_in[18];
  const float* fuse_b2 = (const float*)d_in[19];
  const float* head_W1 = (const float*)d_in[20];
  const float* head_b1 = (const float*)d_in[21];
  const float* head_W2 = (const float*)d_in[22];
  const float* head_b2 = (const float*)d_in[23];

  const int B = in_sizes[1];
  const int T = in_sizes[2];

  char* ws = (char*)d_ws;
  unsigned short* u_p_t   = (unsigned short*)ws;
  int*            seg     = (int*)(ws + 4096);
  unsigned short* u_c_all = (unsigned short*)(ws + 8192);
  float* X    = (float*)(ws + 8192);
  float* zbuf = (float*)(ws + 8192 + (size_t)B * 2048);
  size_t slab_off = 8192 + (size_t)B * 4096;
  float* slabs = (float*)(ws + slab_off);
  float* h1 = slabs;   // slabs dead once zbuf exists

  size_t per_slice = (size_t)B * 4224 * 4;
  int S = 1;
  if (ws_size > slab_off + per_slice) {
    size_t fit = (ws_size - slab_off - ((size_t)(B + 1) * 1024 + 4096)) / per_slice;
    S = (int)(fit < 1 ? 1 : (fit > 4 ? 4 : fit));   // S=4: 4 WGs/CU, ~2 tiles/WG
  }
  float* q_all = (float*)(ws + slab_off + (size_t)S * per_slice);

  const int BT = B / 4;   // 64 b-tiles

  k_qc_gemm<<<dim3(BT + 1, 16), 256, 0, stream>>>(node, tgt_idx, seed,
      Wq_c, Wq_p, q_all, B);
  k_fold<<<dim3(BT + 1, 16), 256, 0, stream>>>(Wk_c, Wk_p, q_all, port_batch,
      u_c_all, u_p_t, seg, T, B);
  attn_kernel<<<dim3(S, B), 256, 0, stream>>>(node, port_index, port_weight,
      u_p_t, u_c_all, seg, slabs, T, S);
  k_slab_gemm<<<dim3(BT, 16, 2), 256, 0, stream>>>(slabs, S, Wv_p, Wv_c, X);
  k_plain_gemm<<<dim3(BT, 16, 2), 256, 0, stream>>>(X, 512, Wo_p, Wo_c,
      nullptr, nullptr, zbuf, 512, 256, 0);
  k_ln_gemm<<<dim3(BT, 16), 256, 0, stream>>>(node, tgt_idx, zbuf,
      ln_g, ln_b, fuse_W1, fuse_b1, h1);
  k_tail3<<<dim3(B), 256, 0, stream>>>(h1, fuse_W2, fuse_b2,
      head_W1, head_b1, head_W2, head_b2, (float*)d_out);
}

// Round 5
// 289.818 us; speedup vs baseline: 2.0228x; 1.0459x over previous
//
#include <hip/hip_runtime.h>
#include <hip/hip_bf16.h>

typedef __attribute__((ext_vector_type(8))) short short8;
typedef __attribute__((ext_vector_type(4))) float floatx4;

#define SCALE 0.17677669529663687f  /* 1/sqrt(32) */

__device__ __forceinline__ unsigned short f2bf(float f) {
  unsigned int x = __float_as_uint(f);
  x += 0x7fffu + ((x >> 16) & 1u);   // RNE
  return (unsigned short)(x >> 16);
}
__device__ __forceinline__ float bf2f(unsigned short u) {
  return __uint_as_float(((unsigned int)u) << 16);
}

// ---------------- setup A: q_all[b,:] = tgt_b @ Wq_c  (row B = seed @ Wq_p) ----------------
__global__ __launch_bounds__(256) void k_qc_gemm(
    const float* __restrict__ node, const int* __restrict__ tgt_idx,
    const float* __restrict__ seed,
    const float* __restrict__ Wq_c, const float* __restrict__ Wq_p,
    float* __restrict__ q_all, int B)
{
  __shared__ float act_l[4 * 256];
  const int tid = threadIdx.x;
  const int bt = blockIdx.x, nt = blockIdx.y;
  const int BT = B >> 2;
  for (int i = tid; i < 4 * 256; i += 256) {
    int m = i >> 8, k = i & 255;
    int b = bt * 4 + m;
    float v = 0.f;
    if (b < B)       v = node[(size_t)tgt_idx[b] * 256 + k];
    else if (b == B) v = seed[k];
    act_l[i] = v;
  }
  __syncthreads();
  const float* W = (bt == BT) ? Wq_p : Wq_c;
  const int m = tid >> 6, lane = tid & 63, ks = lane >> 4, n = lane & 15;
  const int n0 = nt * 16;
  float acc = 0.f;
  const float* Wp = W + (size_t)(ks * 64) * 256 + n0 + n;
  const float* ap = &act_l[m * 256 + ks * 64];
  #pragma unroll 8
  for (int k = 0; k < 64; ++k) acc += ap[k] * Wp[(size_t)k * 256];
  acc += __shfl_xor(acc, 16, 64);
  acc += __shfl_xor(acc, 32, 64);
  const int b = bt * 4 + m;
  if (ks == 0 && b <= B) q_all[(size_t)b * 256 + n0 + n] = acc;
}

// ---------------- setup B: per-head fold u[b][h][d] = sum_j Wk[d, h*32+j] q[b, h*32+j] ----------------
__global__ __launch_bounds__(256) void k_fold(
    const float* __restrict__ Wk_c, const float* __restrict__ Wk_p,
    const float* __restrict__ q_all, const int* __restrict__ port_batch,
    unsigned short* __restrict__ u_c_all, unsigned short* __restrict__ u_p_t,
    int* __restrict__ seg, int T, int B)
{
  const int tid = threadIdx.x;
  const int bt = blockIdx.x, dt = blockIdx.y;
  const int BT = B >> 2;
  if (dt == 0) {
    int key = -1;
    if (bt < BT) { if (tid < 4) key = bt * 4 + tid; }
    else if (tid == 0) key = B;
    if (key >= 0) {
      int lo = 0, hi = T;
      while (lo < hi) { int mid = (lo + hi) >> 1; if (port_batch[mid] < key) lo = mid + 1; else hi = mid; }
      seg[key] = lo;
    }
  }
  const int m = tid >> 6, lane = tid & 63;
  const int b = bt * 4 + m;
  if (b > B) return;
  const float* Wk = (b == B) ? Wk_p : Wk_c;
  const float* q = q_all + (size_t)b * 256;
  #pragma unroll
  for (int t2 = 0; t2 < 2; ++t2) {
    const int idx = t2 * 64 + lane;
    const int h = idx >> 4;
    const int d = dt * 16 + (idx & 15);
    float acc = 0.f;
    const float* wr = Wk + (size_t)d * 256 + h * 32;
    const float* qr = q + h * 32;
    #pragma unroll 8
    for (int j = 0; j < 32; ++j) acc += wr[j] * qr[j];
    unsigned short v = f2bf(acc);
    if (b < B) u_c_all[(size_t)b * 2048 + h * 256 + d] = v;
    else       u_p_t[h * 256 + d] = v;
  }
}

// ---------------- attention: WG (s, b) handles tiles s, s+S, ... of segment b ----------------
// Double-buffered LDS + async-STAGE split (T14): issue tile t+1's 16 row-loads into
// registers BEFORE phase1(t); cvt + ds_write into the other buffer AFTER barrier B.
// HBM gather latency hides under phase1/softmax/phase2. Same 2 barriers/tile, math
// identical to the single-buffer version. LDS ~70 KB -> 2 blocks/CU; S=2 -> ~4 tiles/WG
// so 3 of 4 gathers per WG are hidden.
// LDS layout XOR-swizzled: in-row byte offset ^= ((row>>3)&3)<<5 (kills 8-way phase-2 conflict).
__global__ __launch_bounds__(256, 2) void attn_kernel(
    const float* __restrict__ node,
    const int* __restrict__ port_index,
    const float* __restrict__ port_weight,
    const unsigned short* __restrict__ u_p_t,
    const unsigned short* __restrict__ u_c_all,
    const int* __restrict__ seg,
    float* __restrict__ slabs, int T, int S)
{
  __shared__ __align__(16) unsigned short tok_lds[2][64 * 264];
  __shared__ __align__(16) unsigned short E_t[16 * 72];
  __shared__ float l_lds[16];

  const int tid  = threadIdx.x;
  const int s    = blockIdx.x;
  const int b    = blockIdx.y;
  const int lane = tid & 63;
  const int w    = tid >> 6;
  const int q    = lane >> 4;
  const int n    = lane & 15;

  if (tid < 16) l_lds[tid] = 0.f;

  short8 ufrag[8];
  const unsigned short* ubase = (n < 8) ? (u_p_t + n * 256)
                                        : (u_c_all + (size_t)b * 2048 + (n - 8) * 256);
  #pragma unroll
  for (int s8 = 0; s8 < 8; ++s8)
    ufrag[s8] = *(const short8*)(ubase + q * 8 + s8 * 32);

  const int start  = seg[b];
  const int end    = seg[b + 1];
  const int ntiles = (end - start + 63) >> 6;

  floatx4 sacc[4];
  #pragma unroll
  for (int nt = 0; nt < 4; ++nt) sacc[nt] = (floatx4){0.f, 0.f, 0.f, 0.f};

  // prologue: stage first tile into buf 0 (exposed gather, once per WG)
  if (s < ntiles) {
    const int tbase = start + s * 64;
    int t0 = tbase + w * 16 + n;
    int idxv = port_index[t0 < T ? t0 : T - 1];
    #pragma unroll
    for (int i = 0; i < 16; ++i) {
      int rb = __shfl(idxv, i, 64);
      floatx4 v = *(const floatx4*)(node + (size_t)rb * 256 + lane * 4);
      uint2 pk;
      asm("v_cvt_pk_bf16_f32 %0, %1, %2" : "=v"(pk.x) : "v"(v[0]), "v"(v[1]));
      asm("v_cvt_pk_bf16_f32 %0, %1, %2" : "=v"(pk.y) : "v"(v[2]), "v"(v[3]));
      const int row = w * 16 + i;
      const int swz = ((row >> 3) & 3) << 5;
      *(uint2*)((char*)(tok_lds[0] + row * 264) + ((lane * 8) ^ swz)) = pk;
    }
  }
  __syncthreads();   // l_lds init visible (staging visibility for phase2 covered by barrier A)

  int c = 0;
  for (int it = s; it < ntiles; it += S) {
    const int tbase = start + it * 64;
    const bool hasNext = (it + S) < ntiles;

    // ISSUE-EARLY: next tile's 16 row loads -> registers (no wait; hides under compute)
    floatx4 vreg[16];
    if (hasNext) {
      const int nb = start + (it + S) * 64;
      int t0 = nb + w * 16 + n;
      int idxv = port_index[t0 < T ? t0 : T - 1];
      #pragma unroll
      for (int i = 0; i < 16; ++i) {
        int rb = __shfl(idxv, i, 64);
        vreg[i] = *(const floatx4*)(node + (size_t)rb * 256 + lane * 4);
      }
    }

    float pw[4];
    #pragma unroll
    for (int r = 0; r < 4; ++r) { int tr = tbase + w * 16 + q * 4 + r; pw[r] = port_weight[tr < T ? tr : T - 1]; }

    const unsigned short* tl = tok_lds[c];

    // phase 1: logits = tok_tile[16x256] @ U[256x16]; A-frags from LDS (own wave's rows)
    floatx4 lacc = (floatx4){0.f, 0.f, 0.f, 0.f};
    {
      const int rowA = w * 16 + n;
      const char* abase = (const char*)(tl + rowA * 264);
      const int swzA = ((rowA >> 3) & 3) << 5;
      #pragma unroll
      for (int k = 0; k < 8; ++k) {
        short8 af = *(const short8*)(abase + ((q * 16 + k * 64) ^ swzA));
        lacc = __builtin_amdgcn_mfma_f32_16x16x32_bf16(af, ufrag[k], lacc, 0, 0, 0);
      }
    }
    float lsum = 0.f;
    #pragma unroll
    for (int r = 0; r < 4; ++r) {
      const int tr = tbase + w * 16 + q * 4 + r;
      float e = 0.f;
      if (tr < end) {
        // exp(l*scale + log(pw+eps)) == exp(l*scale) * (pw+eps) -- exact, no logf
        e = __expf(lacc[r] * SCALE) * (pw[r] + 1e-8f);
      }
      unsigned short eb = f2bf(e);
      E_t[n * 72 + w * 16 + q * 4 + r] = eb;       // E^T: [col][token]
      lsum += bf2f(eb);                            // denom consistent with bf16 e
    }
    lsum += __shfl_xor(lsum, 16, 64);
    lsum += __shfl_xor(lsum, 32, 64);
    if (lane < 16) atomicAdd(&l_lds[lane], lsum);
    __syncthreads();   // barrier A: E_t + all waves' tok rows (staged last iter) visible
    // phase 2: sums[16 cols][256 d] += E^T[16x64] @ tok[64x256]; wave w owns d slice
    short8 ea0 = *(const short8*)(E_t + n * 72 + q * 8);
    short8 ea1 = *(const short8*)(E_t + n * 72 + 32 + q * 8);
    const char* tbytes = (const char*)tl;
    const int sq = q << 5;
    #pragma unroll
    for (int nt = 0; nt < 4; ++nt) {
      const int dx = ((w * 64 + nt * 16 + n) * 2) ^ sq;   // swizzled in-row byte offset
      short8 b0, b1;
      #pragma unroll
      for (int j = 0; j < 8; ++j) b0[j] = *(const short*)(tbytes + (q * 8 + j) * 528 + dx);
      #pragma unroll
      for (int j = 0; j < 8; ++j) b1[j] = *(const short*)(tbytes + (32 + q * 8 + j) * 528 + dx);
      sacc[nt] = __builtin_amdgcn_mfma_f32_16x16x32_bf16(ea0, b0, sacc[nt], 0, 0, 0);
      sacc[nt] = __builtin_amdgcn_mfma_f32_16x16x32_bf16(ea1, b1, sacc[nt], 0, 0, 0);
    }
    __syncthreads();   // barrier B: everyone done reading buf c & E_t

    // WRITE-LATE: cvt staged registers, write into the other buffer
    if (hasNext) {
      #pragma unroll
      for (int i = 0; i < 16; ++i) {
        uint2 pk;
        asm("v_cvt_pk_bf16_f32 %0, %1, %2" : "=v"(pk.x) : "v"(vreg[i][0]), "v"(vreg[i][1]));
        asm("v_cvt_pk_bf16_f32 %0, %1, %2" : "=v"(pk.y) : "v"(vreg[i][2]), "v"(vreg[i][3]));
        const int row = w * 16 + i;
        const int swz = ((row >> 3) & 3) << 5;
        *(uint2*)((char*)(tok_lds[c ^ 1] + row * 264) + ((lane * 8) ^ swz)) = pk;
      }
    }
    c ^= 1;
  }

  // epilogue: stage sacc through LDS (tok_lds free), coalesced float4 slab write
  float* stage = (float*)tok_lds;
  #pragma unroll
  for (int nt = 0; nt < 4; ++nt)
    #pragma unroll
    for (int r = 0; r < 4; ++r)
      stage[(q * 4 + r) * 256 + w * 64 + nt * 16 + n] = sacc[nt][r];
  __syncthreads();
  float* sl = slabs + ((size_t)b * S + s) * 4224;
  #pragma unroll
  for (int i = 0; i < 4; ++i) {
    const int row = i * 4 + w;
    const int c0 = (tid & 63) * 4;
    *(floatx4*)(sl + row * 256 + c0) = *(const floatx4*)(stage + row * 256 + c0);
  }
  if (tid < 16) sl[4096 + tid] = l_lds[tid];
}

// ============ staged finalize: batched 4x16 output tiles, K-split waves ============
__global__ __launch_bounds__(256) void k_slab_gemm(
    const float* __restrict__ slabs, int S,
    const float* __restrict__ Wv_p, const float* __restrict__ Wv_c,
    float* __restrict__ X)
{
  __shared__ float act_l[4 * 256];
  __shared__ float lsum[4];
  const int tid = threadIdx.x;
  const int bt = blockIdx.x, nt = blockIdx.y, z = blockIdx.z;
  const int head = nt >> 1;
  const int row = z * 8 + head;
  if (tid < 4) {
    const float* sl = slabs + (size_t)(bt * 4 + tid) * S * 4224;
    float l = 0.f;
    for (int s = 0; s < S; ++s) l += sl[s * 4224 + 4096 + row];
    lsum[tid] = 1.0f / (l + 1e-9f);
  }
  __syncthreads();
  for (int i = tid; i < 4 * 256; i += 256) {
    int m = i >> 8, k = i & 255;
    const float* sl = slabs + (size_t)(bt * 4 + m) * S * 4224;
    float sum = 0.f;
    for (int s = 0; s < S; ++s) sum += sl[s * 4224 + row * 256 + k];
    act_l[i] = sum * lsum[m];
  }
  __syncthreads();
  const int m = tid >> 6, lane = tid & 63, ks = lane >> 4, n = lane & 15;
  const int n0 = nt * 16;
  const float* W = z ? Wv_c : Wv_p;
  float acc = 0.f;
  const float* Wp = W + (size_t)(ks * 64) * 256 + n0 + n;
  const float* ap = &act_l[m * 256 + ks * 64];
  #pragma unroll 8
  for (int k = 0; k < 64; ++k) acc += ap[k] * Wp[(size_t)k * 256];
  acc += __shfl_xor(acc, 16, 64);
  acc += __shfl_xor(acc, 32, 64);
  if (ks == 0)
    X[(size_t)(bt * 4 + m) * 512 + z * 256 + n0 + n] = acc;
}

__global__ __launch_bounds__(256) void k_plain_gemm(
    const float* __restrict__ act, int act_ld,
    const float* __restrict__ W0, const float* __restrict__ W1,
    const float* __restrict__ bias0, const float* __restrict__ bias1,
    float* __restrict__ outp, int out_ld,
    int K, int relu)
{
  __shared__ float act_l[4 * 768];
  const int tid = threadIdx.x;
  const int bt = blockIdx.x, nt = blockIdx.y, z = blockIdx.z;
  const float* W = z ? W1 : W0;
  const float* bias = z ? bias1 : bias0;
  for (int i = tid; i < 4 * K; i += 256) {
    int m = i / K, k = i - m * K;
    act_l[m * K + k] = act[(size_t)(bt * 4 + m) * act_ld + z * K + k];
  }
  __syncthreads();
  const int m = tid >> 6, lane = tid & 63, ks = lane >> 4, n = lane & 15;
  const int n0 = nt * 16;
  const int Kq = K >> 2;
  float acc = 0.f;
  const float* Wp = W + (size_t)(ks * Kq) * 256 + n0 + n;
  const float* ap = &act_l[m * K + ks * Kq];
  #pragma unroll 8
  for (int k = 0; k < Kq; ++k) acc += ap[k] * Wp[(size_t)k * 256];
  acc += __shfl_xor(acc, 16, 64);
  acc += __shfl_xor(acc, 32, 64);
  if (ks == 0) {
    float v = acc + (bias ? bias[n0 + n] : 0.f);
    if (relu) v = fmaxf(v, 0.f);
    outp[(size_t)(bt * 4 + m) * out_ld + z * 256 + n0 + n] = v;
  }
}

__global__ __launch_bounds__(256) void k_ln_gemm(
    const float* __restrict__ node, const int* __restrict__ tgt_idx,
    const float* __restrict__ zbuf,
    const float* __restrict__ ln_g, const float* __restrict__ ln_b,
    const float* __restrict__ fuse_W1, const float* __restrict__ fuse_b1,
    float* __restrict__ h1)
{
  __shared__ float act_l[4 * 768];
  const int tid = threadIdx.x;
  const int bt = blockIdx.x, nt = blockIdx.y;
  for (int i = tid; i < 4 * 256; i += 256) {
    int m = i >> 8, k = i & 255;
    int b = bt * 4 + m;
    float tg = node[(size_t)tgt_idx[b] * 256 + k];
    float C  = zbuf[(size_t)b * 512 + k];
    float Fp = zbuf[(size_t)b * 512 + 256 + k];
    act_l[m * 768 + k]       = tg;
    act_l[m * 768 + 256 + k] = C;
    act_l[m * 768 + 512 + k] = tg + Fp;
  }
  __syncthreads();
  const int m = tid >> 6, lane = tid & 63;
  {
    float s = 0.f;
    for (int k = lane; k < 768; k += 64) s += act_l[m * 768 + k];
    #pragma unroll
    for (int o = 32; o >= 1; o >>= 1) s += __shfl_xor(s, o, 64);
    const float mu = s * (1.0f / 768.0f);
    float v = 0.f;
    for (int k = lane; k < 768; k += 64) { float d = act_l[m * 768 + k] - mu; v += d * d; }
    #pragma unroll
    for (int o = 32; o >= 1; o >>= 1) v += __shfl_xor(v, o, 64);
    const float rstd = 1.0f / sqrtf(v * (1.0f / 768.0f) + 1e-5f);
    for (int k = lane; k < 768; k += 64)
      act_l[m * 768 + k] = (act_l[m * 768 + k] - mu) * rstd * ln_g[k] + ln_b[k];
  }
  __syncthreads();
  const int ks = lane >> 4, n = lane & 15;
  const int n0 = nt * 16;
  float acc = 0.f;
  const float* Wp = fuse_W1 + (size_t)(ks * 192) * 256 + n0 + n;
  const float* ap = &act_l[m * 768 + ks * 192];
  #pragma unroll 8
  for (int k = 0; k < 192; ++k) acc += ap[k] * Wp[(size_t)k * 256];
  acc += __shfl_xor(acc, 16, 64);
  acc += __shfl_xor(acc, 32, 64);
  if (ks == 0)
    h1[(size_t)(bt * 4 + m) * 256 + n0 + n] = fmaxf(acc + fuse_b1[n0 + n], 0.f);
}

// ============ merged last 3 stages: z2 = h1@W2+b2; hh = relu(z2@hW1+b1); out = hh@hW2+b2 ====
__global__ __launch_bounds__(256) void k_tail3(
    const float* __restrict__ h1,
    const float* __restrict__ fuse_W2, const float* __restrict__ fuse_b2,
    const float* __restrict__ head_W1, const float* __restrict__ head_b1,
    const float* __restrict__ head_W2, const float* __restrict__ head_b2,
    float* __restrict__ out)
{
  __shared__ float a_l[256];
  __shared__ float part[4][256];
  __shared__ float red[12];
  const int tid = threadIdx.x;
  const int b = blockIdx.x;
  const int ks = tid >> 6, lane = tid & 63;

  a_l[tid] = h1[(size_t)b * 256 + tid];
  __syncthreads();

  // stage 1: z2 = a @ fuse_W2 + b2   (K=256 split as 4 x 64 across waves)
  {
    floatx4 acc = (floatx4){0.f, 0.f, 0.f, 0.f};
    const float* ap = &a_l[ks * 64];
    const float* wp = fuse_W2 + (size_t)(ks * 64) * 256 + lane * 4;
    #pragma unroll 4
    for (int k = 0; k < 64; ++k) {
      float a = ap[k];
      floatx4 w = *(const floatx4*)(wp + (size_t)k * 256);
      acc[0] += a * w[0]; acc[1] += a * w[1]; acc[2] += a * w[2]; acc[3] += a * w[3];
    }
    *(floatx4*)&part[ks][lane * 4] = acc;
  }
  __syncthreads();
  {
    float v = (part[0][tid] + part[1][tid]) + (part[2][tid] + part[3][tid]) + fuse_b2[tid];
    __syncthreads();           // everyone done reading part & a_l before overwrite
    a_l[tid] = v;
  }
  __syncthreads();

  // stage 2: hh = relu(z2 @ head_W1 + b1)
  {
    floatx4 acc = (floatx4){0.f, 0.f, 0.f, 0.f};
    const float* ap = &a_l[ks * 64];
    const float* wp = head_W1 + (size_t)(ks * 64) * 256 + lane * 4;
    #pragma unroll 4
    for (int k = 0; k < 64; ++k) {
      float a = ap[k];
      floatx4 w = *(const floatx4*)(wp + (size_t)k * 256);
      acc[0] += a * w[0]; acc[1] += a * w[1]; acc[2] += a * w[2]; acc[3] += a * w[3];
    }
    *(floatx4*)&part[ks][lane * 4] = acc;
  }
  __syncthreads();
  {
    float v = (part[0][tid] + part[1][tid]) + (part[2][tid] + part[3][tid]) + head_b1[tid];
    v = fmaxf(v, 0.f);
    __syncthreads();
    a_l[tid] = v;
  }
  __syncthreads();

  // stage 3: out = hh @ head_W2 + b2   (K split 4 ways, wave shfl-reduce, LDS combine)
  {
    float a0 = 0.f, a1 = 0.f, a2 = 0.f;
    for (int k = ks * 64 + lane; k < ks * 64 + 64; k += 64) {
      float h = a_l[k];
      a0 += h * head_W2[k * 3 + 0];
      a1 += h * head_W2[k * 3 + 1];
      a2 += h * head_W2[k * 3 + 2];
    }
    #pragma unroll
    for (int o = 32; o >= 1; o >>= 1) {
      a0 += __shfl_xor(a0, o, 64);
      a1 += __shfl_xor(a1, o, 64);
      a2 += __shfl_xor(a2, o, 64);
    }
    if (lane == 0) { red[ks * 3 + 0] = a0; red[ks * 3 + 1] = a1; red[ks * 3 + 2] = a2; }
  }
  __syncthreads();
  if (tid < 3) {
    out[b * 3 + tid] = (red[0 + tid] + red[3 + tid]) + (red[6 + tid] + red[9 + tid])
                       + head_b2[tid];
  }
}

extern "C" void kernel_launch(void* const* d_in, const int* in_sizes, int n_in,
                              void* d_out, int out_size, void* d_ws, size_t ws_size,
                              hipStream_t stream) {
  const float* node        = (const float*)d_in[0];
  const int*   tgt_idx     = (const int*)d_in[1];
  const int*   port_index  = (const int*)d_in[2];
  const int*   port_batch  = (const int*)d_in[3];
  const float* port_weight = (const float*)d_in[4];
  const float* seed        = (const float*)d_in[5];
  const float* Wq_p = (const float*)d_in[6];
  const float* Wk_p = (const float*)d_in[7];
  const float* Wv_p = (const float*)d_in[8];
  const float* Wo_p = (const float*)d_in[9];
  const float* Wq_c = (const float*)d_in[10];
  const float* Wk_c = (const float*)d_in[11];
  const float* Wv_c = (const float*)d_in[12];
  const float* Wo_c = (const float*)d_in[13];
  const float* ln_g = (const float*)d_in[14];
  const float* ln_b = (const float*)d_in[15];
  const float* fuse_W1 = (const float*)d_in[16];
  const float* fuse_b1 = (const float*)d_in[17];
  const float* fuse_W2 = (const float*)d_in[18];
  const float* fuse_b2 = (const float*)d_in[19];
  const float* head_W1 = (const float*)d_in[20];
  const float* head_b1 = (const float*)d_in[21];
  const float* head_W2 = (const float*)d_in[22];
  const float* head_b2 = (const float*)d_in[23];

  const int B = in_sizes[1];
  const int T = in_sizes[2];

  char* ws = (char*)d_ws;
  unsigned short* u_p_t   = (unsigned short*)ws;
  int*            seg     = (int*)(ws + 4096);
  unsigned short* u_c_all = (unsigned short*)(ws + 8192);
  float* X    = (float*)(ws + 8192);
  float* zbuf = (float*)(ws + 8192 + (size_t)B * 2048);
  size_t slab_off = 8192 + (size_t)B * 4096;
  float* slabs = (float*)(ws + slab_off);
  float* h1 = slabs;   // slabs dead once zbuf exists

  size_t per_slice = (size_t)B * 4224 * 4;
  int S = 1;
  if (ws_size > slab_off + per_slice) {
    size_t fit = (ws_size - slab_off - ((size_t)(B + 1) * 1024 + 4096)) / per_slice;
    S = (int)(fit < 1 ? 1 : (fit > 2 ? 2 : fit));   // S=2: 512 WGs (2/CU), ~4 tiles/WG for pipelining
  }
  float* q_all = (float*)(ws + slab_off + (size_t)S * per_slice);

  const int BT = B / 4;   // 64 b-tiles

  k_qc_gemm<<<dim3(BT + 1, 16), 256, 0, stream>>>(node, tgt_idx, seed,
      Wq_c, Wq_p, q_all, B);
  k_fold<<<dim3(BT + 1, 16), 256, 0, stream>>>(Wk_c, Wk_p, q_all, port_batch,
      u_c_all, u_p_t, seg, T, B);
  attn_kernel<<<dim3(S, B), 256, 0, stream>>>(node, port_index, port_weight,
      u_p_t, u_c_all, seg, slabs, T, S);
  k_slab_gemm<<<dim3(BT, 16, 2), 256, 0, stream>>>(slabs, S, Wv_p, Wv_c, X);
  k_plain_gemm<<<dim3(BT, 16, 2), 256, 0, stream>>>(X, 512, Wo_p, Wo_c,
      nullptr, nullptr, zbuf, 512, 256, 0);
  k_ln_gemm<<<dim3(BT, 16), 256, 0, stream>>>(node, tgt_idx, zbuf,
      ln_g, ln_b, fuse_W1, fuse_b1, h1);
  k_tail3<<<dim3(B), 256, 0, stream>>>(h1, fuse_W2, fuse_b2,
      head_W1, head_b1, head_W2, head_b2, (float*)d_out);
}